// Round 2
// baseline (146.457 us; speedup 1.0000x reference)
//
#include <hip/hip_runtime.h>
#include <hip/hip_bf16.h>

// BalancedBCE: single-pass fused kernel.
// bce(x,t) = max(x,0) - x*t + log1p(exp(-|x|)), t in {0,1} exactly.
// loss = sum_b (1-tmean_b)*pos_bce_b / pos_cnt_tot + sum_b tmean_b*neg_bce_b / neg_cnt_tot
// where tmean_b = pos_cnt_b / S, S = C*H*W = 262144.
// Single pass accumulating (pos_bce_sum, neg_bce_sum, pos_cnt) per sample,
// then a tiny finalize kernel applies the count-derived weights.
//
// R1 tuning: 2048 blocks (32/sample) x 256 thr = 8192 waves -> all co-resident
// at 32 waves/CU (VGPR=24 allows 8 waves/SIMD). Loads batched 2 iters deep
// (4 x 16B in flight/thread) for MLP. Was: 1024 blocks, 16 waves/CU, 45 us
// at 18% HBM / 21% VALU (latency-bound).

#define S_ELEMS (512 * 512)        // per-sample element count (C=1)
#define KPB 32                     // blocks per sample
#define BQ (S_ELEMS / 4)           // float4s per sample = 65536
#define PBQ (BQ / KPB)             // float4s per block  = 2048
#define TPB 256                    // threads per block
#define ITERS (PBQ / TPB)          // 8 float4 iterations per thread

__global__ __launch_bounds__(TPB, 8) void bce_partial(
    const float4* __restrict__ x4, const float4* __restrict__ t4,
    float* __restrict__ part) {
  const int blk = blockIdx.x;
  const int b = blk >> 5;          // blk / KPB
  const int k = blk & (KPB - 1);   // blk % KPB
  const long base = (long)b * BQ + (long)k * PBQ + threadIdx.x;

  float pos_s = 0.f, neg_s = 0.f, pos_c = 0.f;

#pragma unroll
  for (int i = 0; i < ITERS; i += 2) {
    const long i0 = base + (long)i * TPB;
    const long i1 = base + (long)(i + 1) * TPB;
    // issue all four 16B loads before any use
    const float4 xv0 = x4[i0];
    const float4 tv0 = t4[i0];
    const float4 xv1 = x4[i1];
    const float4 tv1 = t4[i1];

    const float xs[8] = {xv0.x, xv0.y, xv0.z, xv0.w, xv1.x, xv1.y, xv1.z, xv1.w};
    const float ts[8] = {tv0.x, tv0.y, tv0.z, tv0.w, tv1.x, tv1.y, tv1.z, tv1.w};
#pragma unroll
    for (int c = 0; c < 8; ++c) {
      const float xc = xs[c];
      const float tc = ts[c];  // exactly 0.0 or 1.0
      const float ax = fabsf(xc);
      const float l1p = __logf(1.f + __expf(-ax));  // log1p(exp(-|x|))
      const float common = fmaxf(xc, 0.f) + l1p;    // bce at t=0
      pos_s = fmaf(tc, common - xc, pos_s);         // bce at t=1 = common - x
      neg_s = fmaf(1.f - tc, common, neg_s);
      pos_c += tc;
    }
  }

  // wave (64-lane) shuffle reduction
#pragma unroll
  for (int off = 32; off > 0; off >>= 1) {
    pos_s += __shfl_down(pos_s, off, 64);
    neg_s += __shfl_down(neg_s, off, 64);
    pos_c += __shfl_down(pos_c, off, 64);
  }

  __shared__ float sm[3][TPB / 64];
  const int lane = threadIdx.x & 63;
  const int wave = threadIdx.x >> 6;
  if (lane == 0) {
    sm[0][wave] = pos_s;
    sm[1][wave] = neg_s;
    sm[2][wave] = pos_c;
  }
  __syncthreads();
  if (threadIdx.x == 0) {
    float p = 0.f, n = 0.f, c = 0.f;
#pragma unroll
    for (int w = 0; w < TPB / 64; ++w) {
      p += sm[0][w];
      n += sm[1][w];
      c += sm[2][w];
    }
    part[blk * 3 + 0] = p;
    part[blk * 3 + 1] = n;
    part[blk * 3 + 2] = c;
  }
}

// One wave: lane b handles sample b (B = 64).
__global__ __launch_bounds__(64) void bce_final(
    const float* __restrict__ part, float* __restrict__ out, int B) {
  const int b = threadIdx.x;
  float p = 0.f, n = 0.f, c = 0.f;
  if (b < B) {
#pragma unroll
    for (int k = 0; k < KPB; ++k) {
      const int blk = b * KPB + k;
      p += part[blk * 3 + 0];
      n += part[blk * 3 + 1];
      c += part[blk * 3 + 2];
    }
  }
  const float tmean = c * (1.f / (float)S_ELEMS);
  float wp = (1.f - tmean) * p;  // weighted positive bce sum for sample b
  float wn = tmean * n;          // weighted negative bce sum for sample b
  float ct = c;
#pragma unroll
  for (int off = 32; off > 0; off >>= 1) {
    wp += __shfl_down(wp, off, 64);
    wn += __shfl_down(wn, off, 64);
    ct += __shfl_down(ct, off, 64);
  }
  if (b == 0) {
    const float pos_cnt = ct;
    const float neg_cnt = (float)B * (float)S_ELEMS - pos_cnt;
    out[0] = wp / pos_cnt + wn / neg_cnt;
  }
}

extern "C" void kernel_launch(void* const* d_in, const int* in_sizes, int n_in,
                              void* d_out, int out_size, void* d_ws, size_t ws_size,
                              hipStream_t stream) {
  const float4* x4 = (const float4*)d_in[0];
  const float4* t4 = (const float4*)d_in[1];
  float* out = (float*)d_out;
  float* part = (float*)d_ws;  // nblocks * 3 floats

  const int total = in_sizes[0];           // 16777216
  const int B = total / S_ELEMS;           // 64
  const int nblocks = B * KPB;             // 2048

  bce_partial<<<nblocks, TPB, 0, stream>>>(x4, t4, part);
  bce_final<<<1, 64, 0, stream>>>(part, out, B);
}

// Round 4
// 139.649 us; speedup vs baseline: 1.0487x; 1.0487x over previous
//
#include <hip/hip_runtime.h>
#include <hip/hip_bf16.h>

// BalancedBCE: single-pass fused kernel.
// bce(x,t) = max(x,0) - x*t + log1p(exp(-|x|)), t in {0,1} exactly.
// loss = sum_b (1-tmean_b)*pos_bce_b / pos_cnt_tot + sum_b tmean_b*neg_bce_b / neg_cnt_tot
// where tmean_b = pos_cnt_b / S, S = C*H*W = 262144.
// Single pass accumulating (pos_bce_sum, neg_bce_sum, pos_cnt) per sample,
// then a tiny finalize kernel applies the count-derived weights.
//
// R2 post-mortem: occupancy 36->60% changed nothing (45 us, 1.5 TB/s HBM).
// Latency-bound on outstanding misses, not occupancy. R3/R4: 4096 blocks (2x
// wave oversubscription), ALL 8 loads (128 B/thread) in flight per batch,
// nontemporal loads (via native clang vector type — HIP float4 is rejected
// by __builtin_nontemporal_load) to avoid L2 thrash on the 134 MB stream.

typedef float v4f __attribute__((ext_vector_type(4)));

#define S_ELEMS (512 * 512)        // per-sample element count (C=1)
#define KPB 64                     // blocks per sample
#define BQ (S_ELEMS / 4)           // float4s per sample = 65536
#define PBQ (BQ / KPB)             // float4s per block  = 1024
#define TPB 256                    // threads per block
#define ITERS (PBQ / TPB)          // 4 float4 iterations per thread

__global__ __launch_bounds__(TPB, 8) void bce_partial(
    const v4f* __restrict__ x4, const v4f* __restrict__ t4,
    float* __restrict__ part) {
  const int blk = blockIdx.x;
  const int b = blk >> 6;          // blk / KPB
  const int k = blk & (KPB - 1);   // blk % KPB
  const long base = (long)b * BQ + (long)k * PBQ + threadIdx.x;

  // Issue ALL loads up front: 8 x 16B = 128 B outstanding per thread.
  v4f xv[ITERS], tv[ITERS];
#pragma unroll
  for (int i = 0; i < ITERS; ++i)
    xv[i] = __builtin_nontemporal_load(&x4[base + (long)i * TPB]);
#pragma unroll
  for (int i = 0; i < ITERS; ++i)
    tv[i] = __builtin_nontemporal_load(&t4[base + (long)i * TPB]);

  float pos_s = 0.f, neg_s = 0.f, pos_c = 0.f;
#pragma unroll
  for (int i = 0; i < ITERS; ++i) {
#pragma unroll
    for (int c = 0; c < 4; ++c) {
      const float xc = xv[i][c];
      const float tc = tv[i][c];  // exactly 0.0 or 1.0
      const float ax = fabsf(xc);
      const float l1p = __logf(1.f + __expf(-ax));  // log1p(exp(-|x|))
      const float common = fmaxf(xc, 0.f) + l1p;    // bce at t=0
      pos_s = fmaf(tc, common - xc, pos_s);         // bce at t=1 = common - x
      neg_s = fmaf(1.f - tc, common, neg_s);
      pos_c += tc;
    }
  }

  // wave (64-lane) shuffle reduction
#pragma unroll
  for (int off = 32; off > 0; off >>= 1) {
    pos_s += __shfl_down(pos_s, off, 64);
    neg_s += __shfl_down(neg_s, off, 64);
    pos_c += __shfl_down(pos_c, off, 64);
  }

  __shared__ float sm[3][TPB / 64];
  const int lane = threadIdx.x & 63;
  const int wave = threadIdx.x >> 6;
  if (lane == 0) {
    sm[0][wave] = pos_s;
    sm[1][wave] = neg_s;
    sm[2][wave] = pos_c;
  }
  __syncthreads();
  if (threadIdx.x == 0) {
    float p = 0.f, n = 0.f, c = 0.f;
#pragma unroll
    for (int w = 0; w < TPB / 64; ++w) {
      p += sm[0][w];
      n += sm[1][w];
      c += sm[2][w];
    }
    part[blk * 3 + 0] = p;
    part[blk * 3 + 1] = n;
    part[blk * 3 + 2] = c;
  }
}

// One wave: lane b handles sample b (B = 64), summing KPB partials each.
__global__ __launch_bounds__(64) void bce_final(
    const float* __restrict__ part, float* __restrict__ out, int B) {
  const int b = threadIdx.x;
  float p = 0.f, n = 0.f, c = 0.f;
  if (b < B) {
#pragma unroll 8
    for (int k = 0; k < KPB; ++k) {
      const int blk = b * KPB + k;
      p += part[blk * 3 + 0];
      n += part[blk * 3 + 1];
      c += part[blk * 3 + 2];
    }
  }
  const float tmean = c * (1.f / (float)S_ELEMS);
  float wp = (1.f - tmean) * p;  // weighted positive bce sum for sample b
  float wn = tmean * n;          // weighted negative bce sum for sample b
  float ct = c;
#pragma unroll
  for (int off = 32; off > 0; off >>= 1) {
    wp += __shfl_down(wp, off, 64);
    wn += __shfl_down(wn, off, 64);
    ct += __shfl_down(ct, off, 64);
  }
  if (b == 0) {
    const float pos_cnt = ct;
    const float neg_cnt = (float)B * (float)S_ELEMS - pos_cnt;
    out[0] = wp / pos_cnt + wn / neg_cnt;
  }
}

extern "C" void kernel_launch(void* const* d_in, const int* in_sizes, int n_in,
                              void* d_out, int out_size, void* d_ws, size_t ws_size,
                              hipStream_t stream) {
  const v4f* x4 = (const v4f*)d_in[0];
  const v4f* t4 = (const v4f*)d_in[1];
  float* out = (float*)d_out;
  float* part = (float*)d_ws;  // nblocks * 3 floats

  const int total = in_sizes[0];           // 16777216
  const int B = total / S_ELEMS;           // 64
  const int nblocks = B * KPB;             // 4096

  bce_partial<<<nblocks, TPB, 0, stream>>>(x4, t4, part);
  bce_final<<<1, 64, 0, stream>>>(part, out, B);
}